// Round 6
// baseline (2664.499 us; speedup 1.0000x reference)
//
#include <hip/hip_runtime.h>
#include <math.h>

typedef unsigned short u16;
typedef __bf16 bf16;
typedef bf16 v8bf __attribute__((ext_vector_type(8)));
typedef float v4f __attribute__((ext_vector_type(4)));
typedef unsigned v4u __attribute__((ext_vector_type(4)));

__device__ __forceinline__ float b2f(u16 u) {
    union { float f; unsigned v; } x;
    x.v = ((unsigned)u) << 16;
    return x.f;
}
__device__ __forceinline__ u16 f2b(float f) {
    union { float f; unsigned v; } x;
    x.f = f;
    unsigned v = x.v;
    return (u16)((v + 0x7FFFu + ((v >> 16) & 1u)) >> 16);  // RNE
}

union Frag { v8bf b; u16 s[8]; unsigned u[4]; v4u u4; };

__device__ __forceinline__ void split8(const float* __restrict__ p, v8bf& hi, v8bf& lo) {
    Frag h, l;
#pragma unroll
    for (int j = 0; j < 8; ++j) {
        float v = p[j];
        u16 a = f2b(v);
        h.s[j] = a;
        l.s[j] = f2b(v - b2f(a));
    }
    hi = h.b; lo = l.b;
}

// 16B fragment as 4 device-coherent (cache-bypassing) u32 loads
__device__ __forceinline__ v8bf load8_agent(const u16* p) {
    Frag r;
    const unsigned* q = (const unsigned*)p;
#pragma unroll
    for (int i = 0; i < 4; ++i)
        r.u[i] = __hip_atomic_load(q + i, __ATOMIC_RELAXED, __HIP_MEMORY_SCOPE_AGENT);
    return r.b;
}

// ---------------------------------------------------------------------------
// hidden f32 -> hhi/hlo bf16 split planes
// ---------------------------------------------------------------------------
__global__ void prep_h(const float* __restrict__ hid, u16* __restrict__ hhi, u16* __restrict__ hlo) {
    int i = blockIdx.x * 256 + threadIdx.x;  // 65536
    float v = hid[i];
    u16 h = f2b(v);
    hhi[i] = h;
    hlo[i] = f2b(v - b2f(h));
}

// ---------------------------------------------------------------------------
// Transpose f32 [R][C] -> bf16 hi/lo [C][R]
// ---------------------------------------------------------------------------
__global__ void transpose_split(const float* __restrict__ src, u16* __restrict__ dhi,
                                u16* __restrict__ dlo, int R, int C) {
    __shared__ float tile[32][33];
    int tid = threadIdx.x;
    int tx = tid & 31, ty = tid >> 5;
    int c0 = blockIdx.x * 32, r0 = blockIdx.y * 32;
#pragma unroll
    for (int i = 0; i < 4; ++i)
        tile[ty + i * 8][tx] = src[(size_t)(r0 + ty + i * 8) * C + c0 + tx];
    __syncthreads();
#pragma unroll
    for (int i = 0; i < 4; ++i) {
        int c = c0 + ty + i * 8;
        float v = tile[tx][ty + i * 8];
        u16 h = f2b(v);
        size_t o = (size_t)c * R + r0 + tx;
        dhi[o] = h;
        dlo[o] = f2b(v - b2f(h));
    }
}

// ---------------------------------------------------------------------------
// xin = E[x] @ W + b0 -> f32 plane [8192][3072]
// ---------------------------------------------------------------------------
__global__ __launch_bounds__(256) void xin_kernel(
        const int* __restrict__ x, const float* __restrict__ E,
        const u16* __restrict__ WThi, const u16* __restrict__ WTlo,
        const float* __restrict__ b0, float* __restrict__ xin) {
    int tid = threadIdx.x;
    int wave = tid >> 6, lane = tid & 63;
    int n = lane & 15, q = lane >> 4;
    int wid = blockIdx.x * 4 + wave;   // 6144 waves
    int bt0 = (wid / 48) * 64;
    int j0 = (wid % 48) * 64;

    const float* arow[4];
#pragma unroll
    for (int mt = 0; mt < 4; ++mt)
        arow[mt] = E + (size_t)x[bt0 + mt * 16 + n] * 256 + q * 8;
    const u16* bhp[4];
    const u16* blp[4];
#pragma unroll
    for (int nt = 0; nt < 4; ++nt) {
        size_t r = (size_t)(j0 + nt * 16 + n) * 256 + q * 8;
        bhp[nt] = WThi + r;
        blp[nt] = WTlo + r;
    }

    v4f acc[4][4];
#pragma unroll
    for (int mt = 0; mt < 4; ++mt)
#pragma unroll
        for (int nt = 0; nt < 4; ++nt) acc[mt][nt] = (v4f){0.f, 0.f, 0.f, 0.f};

    for (int kk = 0; kk < 8; ++kk) {
        v8bf Bh[4], Bl[4];
#pragma unroll
        for (int nt = 0; nt < 4; ++nt) {
            Bh[nt] = *(const v8bf*)(bhp[nt] + kk * 32);
            Bl[nt] = *(const v8bf*)(blp[nt] + kk * 32);
        }
#pragma unroll
        for (int mt = 0; mt < 4; ++mt) {
            v8bf Ah, Al;
            split8(arow[mt] + kk * 32, Ah, Al);
#pragma unroll
            for (int nt = 0; nt < 4; ++nt) {
                acc[mt][nt] = __builtin_amdgcn_mfma_f32_16x16x32_bf16(Ah, Bh[nt], acc[mt][nt], 0, 0, 0);
                acc[mt][nt] = __builtin_amdgcn_mfma_f32_16x16x32_bf16(Ah, Bl[nt], acc[mt][nt], 0, 0, 0);
                acc[mt][nt] = __builtin_amdgcn_mfma_f32_16x16x32_bf16(Al, Bh[nt], acc[mt][nt], 0, 0, 0);
            }
        }
    }
#pragma unroll
    for (int mt = 0; mt < 4; ++mt)
#pragma unroll
        for (int nt = 0; nt < 4; ++nt) {
            int j = j0 + nt * 16 + n;
            float bj = b0[j];
#pragma unroll
            for (int r = 0; r < 4; ++r) {
                int bt = bt0 + mt * 16 + q * 4 + r;
                __builtin_nontemporal_store(acc[mt][nt][r] + bj, &xin[(size_t)bt * 3072 + j]);
            }
        }
}

__global__ void init_barrier(unsigned* __restrict__ bar) {
    bar[threadIdx.x] = 0u;  // 256 words
}

// ---------------------------------------------------------------------------
// Persistent GRU v4: 256 blocks (4 b-groups x 64 u-tiles) x 256 threads.
// U-hi in LDS (96 KB, K-chunk-major -> 2-way bank aliasing = free);
// U-lo streamed from L2 each step (nothing invalidates L2: relaxed polling).
// h exchange via sc-bypass relaxed atomics; barrier = release add + relaxed poll.
// ---------------------------------------------------------------------------
__global__ __launch_bounds__(256, 1) void gru_persistent(
        const u16* __restrict__ UThi, const u16* __restrict__ UTlo,
        const float* __restrict__ b1, const float* __restrict__ xin,
        const float* __restrict__ hid,
        u16* __restrict__ hhi0, u16* __restrict__ hhi1,
        u16* __restrict__ hlo0, u16* __restrict__ hlo1,
        float* __restrict__ out, unsigned* __restrict__ bar) {
    // [3 gates][128 k-chunks][16 cols][8 elems] : read bank = 4n -> 2-way (free)
    __shared__ u16 u_lds[3 * 128 * 16 * 8];   // 98304 B
    __shared__ float red[3][4][256];          // 12288 B
    int tid = threadIdx.x;
    int w = tid >> 6, lane = tid & 63;
    int n = lane & 15, q = lane >> 4;
    int bg = blockIdx.x >> 6;          // 0..3
    int ut = blockIdx.x & 63;          // 0..63
    int b0r = bg * 16;
    int u0 = ut * 16;
    unsigned* cnt = bar + bg * 64;

    // --- Fill LDS with this block's U-hi slice (once) ---
    for (int i = tid; i < 3 * 128 * 16; i += 256) {  // 16B chunks
        int g = i >> 11;             // /2048
        int rem = i & 2047;
        int chunk = rem >> 4;
        int col = rem & 15;
        const v4u* src = (const v4u*)(UThi + (size_t)(g * 1024 + u0 + col) * 1024 + chunk * 8);
        *(v4u*)(u_lds + ((size_t)i) * 8) = *src;
    }
    __syncthreads();

    size_t aoff = (size_t)(b0r + n) * 1024 + w * 256 + q * 8;
    size_t uloff = (size_t)(u0 + n) * 1024 + w * 256 + q * 8;

    // epilogue state
    int bl = tid >> 4, ul = tid & 15;
    int bb = b0r + bl;
    int u = u0 + ul;
    size_t ho = (size_t)bb * 1024 + u;
    float bz = b1[u0 + ul];
    float br_ = b1[1024 + u0 + ul];
    float bh_ = b1[2048 + u0 + ul];
    float hp = hid[ho];

    // prefetch xin for t=0
    float xz = xin[(size_t)bb * 3072 * 128 / 128 * 1 * 0 + (size_t)bb * 128 * 3072 + u];  // placeholder, replaced below
    xz = xin[(size_t)bb * 128 * 3072 + u];
    float xr = xin[(size_t)bb * 128 * 3072 + 1024 + u];
    float xh = xin[(size_t)bb * 128 * 3072 + 2048 + u];

    for (int t = 0; t < 128; ++t) {
        const u16* hhi_in = (t & 1) ? hhi1 : hhi0;
        const u16* hlo_in = (t & 1) ? hlo1 : hlo0;
        u16* hhi_out = (t & 1) ? hhi0 : hhi1;
        u16* hlo_out = (t & 1) ? hlo0 : hlo1;

        // --- A fragments (h, sc-bypass) + streamed U-lo (L2-cached) ---
        v8bf Ah[8], Al[8];
#pragma unroll
        for (int kk = 0; kk < 8; ++kk) {
            Ah[kk] = load8_agent(hhi_in + aoff + kk * 32);
            Al[kk] = load8_agent(hlo_in + aoff + kk * 32);
        }
        v8bf Blo[3][8];
#pragma unroll
        for (int g = 0; g < 3; ++g)
#pragma unroll
            for (int kk = 0; kk < 8; ++kk)
                Blo[g][kk] = *(const v8bf*)(UTlo + uloff + (size_t)g * 1048576 + kk * 32);

        v4f az = {0.f, 0.f, 0.f, 0.f}, ag = az, ah = az;
#pragma unroll
        for (int kk = 0; kk < 8; ++kk) {
            int chunk = w * 32 + kk * 4 + q;
            v8bf Bh0 = *(const v8bf*)(u_lds + ((size_t)(0 * 128 + chunk) * 16 + n) * 8);
            v8bf Bh1 = *(const v8bf*)(u_lds + ((size_t)(1 * 128 + chunk) * 16 + n) * 8);
            v8bf Bh2 = *(const v8bf*)(u_lds + ((size_t)(2 * 128 + chunk) * 16 + n) * 8);
            az = __builtin_amdgcn_mfma_f32_16x16x32_bf16(Ah[kk], Bh0, az, 0, 0, 0);
            ag = __builtin_amdgcn_mfma_f32_16x16x32_bf16(Ah[kk], Bh1, ag, 0, 0, 0);
            ah = __builtin_amdgcn_mfma_f32_16x16x32_bf16(Ah[kk], Bh2, ah, 0, 0, 0);
            az = __builtin_amdgcn_mfma_f32_16x16x32_bf16(Al[kk], Bh0, az, 0, 0, 0);
            ag = __builtin_amdgcn_mfma_f32_16x16x32_bf16(Al[kk], Bh1, ag, 0, 0, 0);
            ah = __builtin_amdgcn_mfma_f32_16x16x32_bf16(Al[kk], Bh2, ah, 0, 0, 0);
            az = __builtin_amdgcn_mfma_f32_16x16x32_bf16(Ah[kk], Blo[0][kk], az, 0, 0, 0);
            ag = __builtin_amdgcn_mfma_f32_16x16x32_bf16(Ah[kk], Blo[1][kk], ag, 0, 0, 0);
            ah = __builtin_amdgcn_mfma_f32_16x16x32_bf16(Ah[kk], Blo[2][kk], ah, 0, 0, 0);
        }
#pragma unroll
        for (int r = 0; r < 4; ++r) {
            int idx = (q * 4 + r) * 16 + n;  // row(m)=quad*4+reg, col(n)=lane&15
            red[0][w][idx] = az[r];
            red[1][w][idx] = ag[r];
            red[2][w][idx] = ah[r];
        }
        __syncthreads();

        // --- Epilogue (all 256 threads) ---
        float rz = red[0][0][tid] + red[0][1][tid] + red[0][2][tid] + red[0][3][tid] + bz;
        float rr = red[1][0][tid] + red[1][1][tid] + red[1][2][tid] + red[1][3][tid] + br_;
        float rh = red[2][0][tid] + red[2][1][tid] + red[2][2][tid] + red[2][3][tid] + bh_;

        size_t bt = (size_t)bb * 128 + t;
        float z = 1.f / (1.f + expf(-(xz + rz)));
        float rg = 1.f / (1.f + expf(-(xr + rr)));
        float hh = tanhf(xh + rg * rh);
        float hn = z * hp + (1.f - z) * hh;
        hp = hn;

        __builtin_nontemporal_store(hn, &out[bt * 1024 + u]);
        if (t == 127) __builtin_nontemporal_store(hn, &out[8388608 + ho]);

        // publish h (split, packed pairs, sc-bypass)
        u16 myhi = f2b(hn);
        u16 mylo = f2b(hn - b2f(myhi));
        float hn_x = __shfl_xor(hn, 1);
        u16 ohi = f2b(hn_x);
        u16 olo = f2b(hn_x - b2f(ohi));
        if ((tid & 1) == 0) {
            unsigned hi32 = (unsigned)myhi | ((unsigned)ohi << 16);
            unsigned lo32 = (unsigned)mylo | ((unsigned)olo << 16);
            __hip_atomic_store((unsigned*)(hhi_out + ho), hi32, __ATOMIC_RELAXED, __HIP_MEMORY_SCOPE_AGENT);
            __hip_atomic_store((unsigned*)(hlo_out + ho), lo32, __ATOMIC_RELAXED, __HIP_MEMORY_SCOPE_AGENT);
        }

        // prefetch next step's xin (hidden behind the barrier)
        if (t < 127) {
            size_t xo = (bt + 1) * 3072;
            xz = xin[xo + u];
            xr = xin[xo + 1024 + u];
            xh = xin[xo + 2048 + u];
        }

        // --- Barrier: release add + RELAXED poll (no buffer_inv, ever) ---
        __syncthreads();   // all waves drain their h stores (vmcnt0 before s_barrier)
        if (tid == 0) {
            __hip_atomic_fetch_add(cnt, 1u, __ATOMIC_RELEASE, __HIP_MEMORY_SCOPE_AGENT);
            unsigned target = 64u * (unsigned)(t + 1);
            while (__hip_atomic_load(cnt, __ATOMIC_RELAXED, __HIP_MEMORY_SCOPE_AGENT) < target)
                __builtin_amdgcn_s_sleep(1);
        }
        __syncthreads();
    }
}

extern "C" void kernel_launch(void* const* d_in, const int* in_sizes, int n_in,
                              void* d_out, int out_size, void* d_ws, size_t ws_size,
                              hipStream_t stream) {
    const int* x = (const int*)d_in[0];
    const float* hid = (const float*)d_in[1];
    const float* E = (const float*)d_in[2];
    const float* W = (const float*)d_in[3];
    const float* U = (const float*)d_in[4];
    const float* b = (const float*)d_in[5];
    float* out = (float*)d_out;

    char* ws = (char*)d_ws;
    u16* hhi0 = (u16*)(ws + 0);                // 131072
    u16* hhi1 = (u16*)(ws + 131072);           // 131072
    u16* hlo0 = (u16*)(ws + 262144);           // 131072
    u16* hlo1 = (u16*)(ws + 393216);           // 131072
    u16* UThi = (u16*)(ws + 524288);           // 6291456
    u16* UTlo = (u16*)(ws + 6815744);          // 6291456
    u16* WThi = (u16*)(ws + 13107200);         // 1572864 (dead after xin_kernel)
    u16* WTlo = (u16*)(ws + 14680064);         // 1572864
    float* xin = (float*)(ws + 16777216);      // 100663296 -> total 117440512
    unsigned* bar = (unsigned*)(ws + 13107200);  // reuse dead WThi region

    prep_h<<<256, 256, 0, stream>>>(hid, hhi0, hlo0);
    transpose_split<<<dim3(96, 32), 256, 0, stream>>>(U, UThi, UTlo, 1024, 3072);
    transpose_split<<<dim3(96, 8), 256, 0, stream>>>(W, WThi, WTlo, 256, 3072);
    xin_kernel<<<1536, 256, 0, stream>>>(x, E, WThi, WTlo, b, xin);
    init_barrier<<<1, 256, 0, stream>>>(bar);
    gru_persistent<<<256, 256, 0, stream>>>(UThi, UTlo, b + 3072, xin, hid,
                                            hhi0, hhi1, hlo0, hlo1, out, bar);
}

// Round 7
// 1253.173 us; speedup vs baseline: 2.1262x; 2.1262x over previous
//
#include <hip/hip_runtime.h>
#include <math.h>

typedef unsigned short u16;
typedef __bf16 bf16;
typedef bf16 v8bf __attribute__((ext_vector_type(8)));
typedef float v4f __attribute__((ext_vector_type(4)));
typedef unsigned v4u __attribute__((ext_vector_type(4)));

__device__ __forceinline__ float b2f(u16 u) {
    union { float f; unsigned v; } x;
    x.v = ((unsigned)u) << 16;
    return x.f;
}
__device__ __forceinline__ u16 f2b(float f) {
    union { float f; unsigned v; } x;
    x.f = f;
    unsigned v = x.v;
    return (u16)((v + 0x7FFFu + ((v >> 16) & 1u)) >> 16);  // RNE
}

union Frag { v8bf b; u16 s[8]; unsigned u[4]; v4u u4; };

__device__ __forceinline__ void split8(const float* __restrict__ p, v8bf& hi, v8bf& lo) {
    Frag h, l;
#pragma unroll
    for (int j = 0; j < 8; ++j) {
        float v = p[j];
        u16 a = f2b(v);
        h.s[j] = a;
        l.s[j] = f2b(v - b2f(a));
    }
    hi = h.b; lo = l.b;
}

// Coherent (L1/L2-bypassing) 16B vector load; caller must s_waitcnt vmcnt(0).
__device__ __forceinline__ v8bf load16_sc(const u16* p) {
    v4u r;
    asm volatile("global_load_dwordx4 %0, %1, off sc0 sc1" : "=v"(r) : "v"(p) : "memory");
    Frag f; f.u4 = r;
    return f.b;
}

// ---------------------------------------------------------------------------
__global__ void prep_h(const float* __restrict__ hid, u16* __restrict__ hhi, u16* __restrict__ hlo) {
    int i = blockIdx.x * 256 + threadIdx.x;  // 65536
    float v = hid[i];
    u16 h = f2b(v);
    hhi[i] = h;
    hlo[i] = f2b(v - b2f(h));
}

// ---------------------------------------------------------------------------
__global__ void transpose_split(const float* __restrict__ src, u16* __restrict__ dhi,
                                u16* __restrict__ dlo, int R, int C) {
    __shared__ float tile[32][33];
    int tid = threadIdx.x;
    int tx = tid & 31, ty = tid >> 5;
    int c0 = blockIdx.x * 32, r0 = blockIdx.y * 32;
#pragma unroll
    for (int i = 0; i < 4; ++i)
        tile[ty + i * 8][tx] = src[(size_t)(r0 + ty + i * 8) * C + c0 + tx];
    __syncthreads();
#pragma unroll
    for (int i = 0; i < 4; ++i) {
        int c = c0 + ty + i * 8;
        float v = tile[tx][ty + i * 8];
        u16 h = f2b(v);
        size_t o = (size_t)c * R + r0 + tx;
        dhi[o] = h;
        dlo[o] = f2b(v - b2f(h));
    }
}

// ---------------------------------------------------------------------------
// xin = E[x] @ W + b0 -> f32 plane [8192][3072]
// ---------------------------------------------------------------------------
__global__ __launch_bounds__(256) void xin_kernel(
        const int* __restrict__ x, const float* __restrict__ E,
        const u16* __restrict__ WThi, const u16* __restrict__ WTlo,
        const float* __restrict__ b0, float* __restrict__ xin) {
    int tid = threadIdx.x;
    int wave = tid >> 6, lane = tid & 63;
    int n = lane & 15, q = lane >> 4;
    int wid = blockIdx.x * 4 + wave;   // 6144 waves
    int bt0 = (wid / 48) * 64;
    int j0 = (wid % 48) * 64;

    const float* arow[4];
#pragma unroll
    for (int mt = 0; mt < 4; ++mt)
        arow[mt] = E + (size_t)x[bt0 + mt * 16 + n] * 256 + q * 8;
    const u16* bhp[4];
    const u16* blp[4];
#pragma unroll
    for (int nt = 0; nt < 4; ++nt) {
        size_t r = (size_t)(j0 + nt * 16 + n) * 256 + q * 8;
        bhp[nt] = WThi + r;
        blp[nt] = WTlo + r;
    }

    v4f acc[4][4];
#pragma unroll
    for (int mt = 0; mt < 4; ++mt)
#pragma unroll
        for (int nt = 0; nt < 4; ++nt) acc[mt][nt] = (v4f){0.f, 0.f, 0.f, 0.f};

    for (int kk = 0; kk < 8; ++kk) {
        v8bf Bh[4], Bl[4];
#pragma unroll
        for (int nt = 0; nt < 4; ++nt) {
            Bh[nt] = *(const v8bf*)(bhp[nt] + kk * 32);
            Bl[nt] = *(const v8bf*)(blp[nt] + kk * 32);
        }
#pragma unroll
        for (int mt = 0; mt < 4; ++mt) {
            v8bf Ah, Al;
            split8(arow[mt] + kk * 32, Ah, Al);
#pragma unroll
            for (int nt = 0; nt < 4; ++nt) {
                acc[mt][nt] = __builtin_amdgcn_mfma_f32_16x16x32_bf16(Ah, Bh[nt], acc[mt][nt], 0, 0, 0);
                acc[mt][nt] = __builtin_amdgcn_mfma_f32_16x16x32_bf16(Ah, Bl[nt], acc[mt][nt], 0, 0, 0);
                acc[mt][nt] = __builtin_amdgcn_mfma_f32_16x16x32_bf16(Al, Bh[nt], acc[mt][nt], 0, 0, 0);
            }
        }
    }
#pragma unroll
    for (int mt = 0; mt < 4; ++mt)
#pragma unroll
        for (int nt = 0; nt < 4; ++nt) {
            int j = j0 + nt * 16 + n;
            float bj = b0[j];
#pragma unroll
            for (int r = 0; r < 4; ++r) {
                int bt = bt0 + mt * 16 + q * 4 + r;
                __builtin_nontemporal_store(acc[mt][nt][r] + bj, &xin[(size_t)bt * 3072 + j]);
            }
        }
}

__global__ void init_barrier(unsigned* __restrict__ bar) {
    bar[threadIdx.x] = 0u;  // 256 flags: 4 groups x 64
}

// ---------------------------------------------------------------------------
// Persistent GRU v5: 256 blocks (4 b-groups x 64 u-tiles) x 512 threads.
// U-hi in LDS (padded layout); U-lo streamed from L2. Flag-array barrier:
// per-block epoch store + wave-parallel poll (ZERO atomic RMW contention).
// ---------------------------------------------------------------------------
__global__ __launch_bounds__(512, 1) void gru_persistent(
        const u16* __restrict__ UThi, const u16* __restrict__ UTlo,
        const float* __restrict__ b1, const float* __restrict__ xin,
        const float* __restrict__ hid,
        u16* __restrict__ hhi0, u16* __restrict__ hhi1,
        u16* __restrict__ hlo0, u16* __restrict__ hlo1,
        float* __restrict__ out, unsigned* __restrict__ bar) {
    // [3 gates][128 chunks][17 col-slots (16 used + pad)][8 elems]
    __shared__ u16 u_lds[3 * 128 * 17 * 8];   // 104448 B
    __shared__ float red[3][8][256];          // 24576 B
    int tid = threadIdx.x;
    int w = tid >> 6, lane = tid & 63;
    int n = lane & 15, q = lane >> 4;
    int bg = blockIdx.x >> 6;          // 0..3
    int ut = blockIdx.x & 63;          // 0..63
    int b0r = bg * 16;
    int u0 = ut * 16;
    unsigned* flags = bar + bg * 64;   // this group's 64 flags (256B apart)

    // --- Fill LDS with this block's U-hi slice (once) ---
    for (int i = tid; i < 3 * 128 * 16; i += 512) {  // 16B chunks
        int g = i >> 11;
        int rem = i & 2047;
        int chunk = rem >> 4;
        int col = rem & 15;
        *(v4u*)(u_lds + (size_t)((g * 128 + chunk) * 17 + col) * 8) =
            *(const v4u*)(UThi + (size_t)(g * 1024 + u0 + col) * 1024 + chunk * 8);
    }
    __syncthreads();

    size_t aoff = (size_t)(b0r + n) * 1024 + w * 128 + q * 8;
    size_t uloff = (size_t)(u0 + n) * 1024 + w * 128 + q * 8;

    // epilogue state (tid < 256)
    int bl = tid >> 4, ul = tid & 15;
    int bb = b0r + bl;
    int u = u0 + ul;
    size_t ho = (size_t)bb * 1024 + u;
    float bz = 0.f, br_ = 0.f, bh_ = 0.f, hp = 0.f;
    float xz = 0.f, xr = 0.f, xh = 0.f;
    if (tid < 256) {
        bz = b1[u0 + ul];
        br_ = b1[1024 + u0 + ul];
        bh_ = b1[2048 + u0 + ul];
        hp = hid[ho];
        size_t xo = (size_t)bb * 128 * 3072;
        xz = xin[xo + u];
        xr = xin[xo + 1024 + u];
        xh = xin[xo + 2048 + u];
    }

    for (int t = 0; t < 128; ++t) {
        const u16* hhi_in = (t & 1) ? hhi1 : hhi0;
        const u16* hlo_in = (t & 1) ? hlo1 : hlo0;
        u16* hhi_out = (t & 1) ? hhi0 : hhi1;
        u16* hlo_out = (t & 1) ? hlo0 : hlo1;

        // --- A fragments: coherent dwordx4 loads, all issued, one drain ---
        v8bf Ah[4], Al[4];
#pragma unroll
        for (int kk = 0; kk < 4; ++kk) {
            Ah[kk] = load16_sc(hhi_in + aoff + kk * 32);
            Al[kk] = load16_sc(hlo_in + aoff + kk * 32);
        }
        // U-lo stream (L2-resident; compiler-tracked loads)
        v8bf Blo[3][4];
#pragma unroll
        for (int g = 0; g < 3; ++g)
#pragma unroll
            for (int kk = 0; kk < 4; ++kk)
                Blo[g][kk] = *(const v8bf*)(UTlo + uloff + (size_t)g * 1048576 + kk * 32);
        asm volatile("s_waitcnt vmcnt(0)" ::: "memory");

        v4f az = {0.f, 0.f, 0.f, 0.f}, ag = az, ah = az;
#pragma unroll
        for (int kk = 0; kk < 4; ++kk) {
            int chunk = w * 16 + kk * 4 + q;
            const u16* lp = u_lds + (size_t)(chunk * 17 + n) * 8;
            v8bf Bh0 = *(const v8bf*)(lp);
            v8bf Bh1 = *(const v8bf*)(lp + 128 * 17 * 8);
            v8bf Bh2 = *(const v8bf*)(lp + 2 * 128 * 17 * 8);
            az = __builtin_amdgcn_mfma_f32_16x16x32_bf16(Ah[kk], Bh0, az, 0, 0, 0);
            ag = __builtin_amdgcn_mfma_f32_16x16x32_bf16(Ah[kk], Bh1, ag, 0, 0, 0);
            ah = __builtin_amdgcn_mfma_f32_16x16x32_bf16(Ah[kk], Bh2, ah, 0, 0, 0);
            az = __builtin_amdgcn_mfma_f32_16x16x32_bf16(Al[kk], Bh0, az, 0, 0, 0);
            ag = __builtin_amdgcn_mfma_f32_16x16x32_bf16(Al[kk], Bh1, ag, 0, 0, 0);
            ah = __builtin_amdgcn_mfma_f32_16x16x32_bf16(Al[kk], Bh2, ah, 0, 0, 0);
            az = __builtin_amdgcn_mfma_f32_16x16x32_bf16(Ah[kk], Blo[0][kk], az, 0, 0, 0);
            ag = __builtin_amdgcn_mfma_f32_16x16x32_bf16(Ah[kk], Blo[1][kk], ag, 0, 0, 0);
            ah = __builtin_amdgcn_mfma_f32_16x16x32_bf16(Ah[kk], Blo[2][kk], ah, 0, 0, 0);
        }
#pragma unroll
        for (int r = 0; r < 4; ++r) {
            int idx = (q * 4 + r) * 16 + n;  // row(m)=quad*4+reg, col(n)=lane&15
            red[0][w][idx] = az[r];
            red[1][w][idx] = ag[r];
            red[2][w][idx] = ah[r];
        }
        __syncthreads();

        if (tid < 256) {
            float rz = bz, rr = br_, rh = bh_;
#pragma unroll
            for (int ww = 0; ww < 8; ++ww) {
                rz += red[0][ww][tid];
                rr += red[1][ww][tid];
                rh += red[2][ww][tid];
            }
            size_t bt = (size_t)bb * 128 + t;
            float z = 1.f / (1.f + expf(-(xz + rz)));
            float rg = 1.f / (1.f + expf(-(xr + rr)));
            float hh = tanhf(xh + rg * rh);
            float hn = z * hp + (1.f - z) * hh;
            hp = hn;

            __builtin_nontemporal_store(hn, &out[bt * 1024 + u]);
            if (t == 127) __builtin_nontemporal_store(hn, &out[8388608 + ho]);

            // publish h (split, packed pairs, coherent stores)
            u16 myhi = f2b(hn);
            u16 mylo = f2b(hn - b2f(myhi));
            float hn_x = __shfl_xor(hn, 1);
            u16 ohi = f2b(hn_x);
            u16 olo = f2b(hn_x - b2f(ohi));
            if ((tid & 1) == 0) {
                unsigned hi32 = (unsigned)myhi | ((unsigned)ohi << 16);
                unsigned lo32 = (unsigned)mylo | ((unsigned)olo << 16);
                __hip_atomic_store((unsigned*)(hhi_out + ho), hi32, __ATOMIC_RELAXED, __HIP_MEMORY_SCOPE_AGENT);
                __hip_atomic_store((unsigned*)(hlo_out + ho), lo32, __ATOMIC_RELAXED, __HIP_MEMORY_SCOPE_AGENT);
            }

            // prefetch next step's xin (hidden behind the barrier)
            if (t < 127) {
                size_t xo = (bt + 1) * 3072;
                xz = xin[xo + u];
                xr = xin[xo + 1024 + u];
                xh = xin[xo + 2048 + u];
            }
        }

        if (t < 127) {
            // --- Flag-array barrier: store own epoch, poll 64 flags lane-wise
            __syncthreads();   // drains all waves' h stores (vmcnt(0) before s_barrier)
            if (tid < 64) {
                if (tid == 0)
                    __hip_atomic_store(&flags[ut], (unsigned)(t + 1), __ATOMIC_RELAXED, __HIP_MEMORY_SCOPE_AGENT);
                unsigned target = (unsigned)(t + 1);
                while (true) {
                    unsigned v = __hip_atomic_load(&flags[tid], __ATOMIC_RELAXED, __HIP_MEMORY_SCOPE_AGENT);
                    if (__all(v >= target)) break;
                    __builtin_amdgcn_s_sleep(2);
                }
            }
            __syncthreads();
        }
    }
}

extern "C" void kernel_launch(void* const* d_in, const int* in_sizes, int n_in,
                              void* d_out, int out_size, void* d_ws, size_t ws_size,
                              hipStream_t stream) {
    const int* x = (const int*)d_in[0];
    const float* hid = (const float*)d_in[1];
    const float* E = (const float*)d_in[2];
    const float* W = (const float*)d_in[3];
    const float* U = (const float*)d_in[4];
    const float* b = (const float*)d_in[5];
    float* out = (float*)d_out;

    char* ws = (char*)d_ws;
    u16* hhi0 = (u16*)(ws + 0);                // 131072
    u16* hhi1 = (u16*)(ws + 131072);           // 131072
    u16* hlo0 = (u16*)(ws + 262144);           // 131072
    u16* hlo1 = (u16*)(ws + 393216);           // 131072
    u16* UThi = (u16*)(ws + 524288);           // 6291456
    u16* UTlo = (u16*)(ws + 6815744);          // 6291456
    u16* WThi = (u16*)(ws + 13107200);         // 1572864 (dead after xin_kernel)
    u16* WTlo = (u16*)(ws + 14680064);         // 1572864
    float* xin = (float*)(ws + 16777216);      // 100663296 -> total 117440512
    unsigned* bar = (unsigned*)(ws + 13107200);  // reuse dead WThi region

    prep_h<<<256, 256, 0, stream>>>(hid, hhi0, hlo0);
    transpose_split<<<dim3(96, 32), 256, 0, stream>>>(U, UThi, UTlo, 1024, 3072);
    transpose_split<<<dim3(96, 8), 256, 0, stream>>>(W, WThi, WTlo, 256, 3072);
    xin_kernel<<<1536, 256, 0, stream>>>(x, E, WThi, WTlo, b, xin);
    init_barrier<<<1, 256, 0, stream>>>(bar);
    gru_persistent<<<256, 512, 0, stream>>>(UThi, UTlo, b + 3072, xin, hid,
                                            hhi0, hhi1, hlo0, hlo1, out, bar);
}